// Round 13
// baseline (894.980 us; speedup 1.0000x reference)
//
#include <hip/hip_runtime.h>
#include <hip/hip_bf16.h>
#include <math.h>
#include <stdint.h>
#include <limits.h>

#define NN 100000
#define NE 800000
#define PB 512                    // blocks for argmax/lse partial reduction
#define NDB 512                   // blocks for k_dense (BN-stat partials)
#define NEGBIG (-1e30f)

typedef __hip_bfloat16 bf16;

__device__ __forceinline__ float bf2f(unsigned short u)
{
  union { unsigned v; float f; } x; x.v = ((unsigned)u) << 16; return x.f;
}
__device__ __forceinline__ unsigned short f2bf(float f)
{
  bf16 h = __float2bfloat16(f);
  return *reinterpret_cast<unsigned short*>(&h);
}
__device__ __forceinline__ unsigned pk2(float a, float b)
{
  return (unsigned)f2bf(a) | ((unsigned)f2bf(b) << 16);
}
#define LO16(u) ((unsigned short)((u) & 0xffffu))
#define HI16(u) ((unsigned short)((u) >> 16))

// ---------------- threefry2x32-20 (JAX PRNG) ----------------
__device__ __forceinline__ uint2 tf_dev(unsigned k0, unsigned k1, unsigned x0, unsigned x1)
{
  const unsigned ks2 = k0 ^ k1 ^ 0x1BD11BDAu;
#define TFR(r) { x0 += x1; x1 = (x1 << r) | (x1 >> (32 - r)); x1 ^= x0; }
  x0 += k0; x1 += k1;
  TFR(13) TFR(15) TFR(26) TFR(6)
  x0 += k1; x1 += ks2 + 1u;
  TFR(17) TFR(29) TFR(16) TFR(24)
  x0 += ks2; x1 += k0 + 2u;
  TFR(13) TFR(15) TFR(26) TFR(6)
  x0 += k0; x1 += k1 + 3u;
  TFR(17) TFR(29) TFR(16) TFR(24)
  x0 += k1; x1 += ks2 + 4u;
  TFR(13) TFR(15) TFR(26) TFR(6)
  x0 += ks2; x1 += k0 + 5u;
#undef TFR
  return make_uint2(x0, x1);
}

static void tf_host(unsigned k0, unsigned k1, unsigned x0, unsigned x1,
                    unsigned* o0, unsigned* o1)
{
  const unsigned ks2 = k0 ^ k1 ^ 0x1BD11BDAu;
#define TFR(r) { x0 += x1; x1 = (x1 << r) | (x1 >> (32 - r)); x1 ^= x0; }
  x0 += k0; x1 += k1;
  TFR(13) TFR(15) TFR(26) TFR(6)
  x0 += k1; x1 += ks2 + 1u;
  TFR(17) TFR(29) TFR(16) TFR(24)
  x0 += ks2; x1 += k0 + 2u;
  TFR(13) TFR(15) TFR(26) TFR(6)
  x0 += k0; x1 += k1 + 3u;
  TFR(17) TFR(29) TFR(16) TFR(24)
  x0 += k1; x1 += ks2 + 4u;
  TFR(13) TFR(15) TFR(26) TFR(6)
  x0 += ks2; x1 += k0 + 5u;
#undef TFR
  *o0 = x0; *o1 = x1;
}

__device__ __forceinline__ float gumbel_of(unsigned ka, unsigned kb, int i)
{
  uint2 c = tf_dev(ka, kb, 0u, (unsigned)i);
  unsigned bits = c.x ^ c.y;
  float f = __uint_as_float((bits >> 9) | 0x3f800000u) - 1.0f;
  const float TINYF = 1.17549435e-38f;
  float u = fmaxf(TINYF, f + TINYF);
  return -logf(-logf(u));
}

// ---------------- CSR build ----------------
__global__ __launch_bounds__(256) void k_zero2(int* __restrict__ a, int* __restrict__ b)
{
  int i = blockIdx.x * 256 + threadIdx.x;
  if (i < NN) { a[i] = 0; b[i] = 0; }
}

__global__ __launch_bounds__(256) void k_hist(const int* __restrict__ edst, int* __restrict__ deg)
{
  int e = blockIdx.x * 256 + threadIdx.x;
  if (e < NE) atomicAdd(&deg[edst[e]], 1);
}

__global__ __launch_bounds__(1024) void k_scan(const int* __restrict__ deg, int* __restrict__ rowptr)
{
  __shared__ int wsum[16];
  __shared__ int chtot;
  const int t = threadIdx.x;
  const int lane = t & 63;
  const int wv = t >> 6;
  int carry = 0;
  for (int base = 0; base < NN; base += 4096) {
    int i0 = base + t * 4;
    int d0 = 0, d1 = 0, d2 = 0, d3 = 0;
    if (i0 + 3 < NN) { int4 dd = *(const int4*)(deg + i0); d0 = dd.x; d1 = dd.y; d2 = dd.z; d3 = dd.w; }
    else {
      if (i0     < NN) d0 = deg[i0];
      if (i0 + 1 < NN) d1 = deg[i0 + 1];
      if (i0 + 2 < NN) d2 = deg[i0 + 2];
      if (i0 + 3 < NN) d3 = deg[i0 + 3];
    }
    int tsum = d0 + d1 + d2 + d3;
    int sc = tsum;
    #pragma unroll
    for (int off = 1; off < 64; off <<= 1) { int o = __shfl_up(sc, off); if (lane >= off) sc += o; }
    if (lane == 63) wsum[wv] = sc;
    __syncthreads();
    if (wv == 0 && lane < 16) {
      int wval = wsum[lane];
      int wsc = wval;
      #pragma unroll
      for (int off = 1; off < 16; off <<= 1) { int o = __shfl_up(wsc, off); if (lane >= off) wsc += o; }
      if (lane == 15) chtot = wsc;
      wsum[lane] = wsc - wval;  // exclusive
    }
    __syncthreads();
    int excl = carry + wsum[wv] + (sc - tsum);
    if (i0     < NN) rowptr[i0]     = excl;
    if (i0 + 1 < NN) rowptr[i0 + 1] = excl + d0;
    if (i0 + 2 < NN) rowptr[i0 + 2] = excl + d0 + d1;
    if (i0 + 3 < NN) rowptr[i0 + 3] = excl + d0 + d1 + d2;
    carry += chtot;
    __syncthreads();
  }
  if (t == 0) rowptr[NN] = carry;
}

__global__ __launch_bounds__(256) void k_scatter(
    const int* __restrict__ esrc, const int* __restrict__ edst,
    const float* __restrict__ lat, const int* __restrict__ rowptr,
    int* __restrict__ fill, int2* __restrict__ csr)
{
  int e = blockIdx.x * 256 + threadIdx.x;
  if (e >= NE) return;
  int d = edst[e];
  int pos = rowptr[d] + atomicAdd(&fill[d], 1);
  csr[pos] = make_int2(esrc[e], __float_as_int(lat[e]));
}

// ---------------- layer 1 q/kv/skip (Cin = 2); all packed bf16 ----------------
__global__ __launch_bounds__(256) void k_qkvs_first(
    const float* __restrict__ nt, const float* __restrict__ rq,
    const float* __restrict__ qw, const float* __restrict__ qbv,
    const float* __restrict__ kw, const float* __restrict__ kbv,
    const float* __restrict__ vw, const float* __restrict__ vbv,
    const float* __restrict__ sw, const float* __restrict__ sbv,
    unsigned* __restrict__ q, unsigned short* __restrict__ kv, unsigned* __restrict__ sk)
{
  int idx = blockIdx.x * 256 + threadIdx.x;   // over NN*64
  if (idx >= NN * 64) return;
  int n = idx >> 6, l = idx & 63;
  int j0 = 2 * l, j1 = 2 * l + 1;
  float a = nt[n], b = rq[n];
  float q0 = (a * qw[2 * j0] + b * qw[2 * j0 + 1]) + qbv[j0];
  float q1 = (a * qw[2 * j1] + b * qw[2 * j1 + 1]) + qbv[j1];
  q[idx] = pk2(q0, q1);
  ushort4 kvo;
  kvo.x = f2bf((a * kw[2 * j0] + b * kw[2 * j0 + 1]) + kbv[j0]);
  kvo.y = f2bf((a * kw[2 * j1] + b * kw[2 * j1 + 1]) + kbv[j1]);
  kvo.z = f2bf((a * vw[2 * j0] + b * vw[2 * j0 + 1]) + vbv[j0]);
  kvo.w = f2bf((a * vw[2 * j1] + b * vw[2 * j1 + 1]) + vbv[j1]);
  ((ushort4*)kv)[idx] = kvo;
  float s0 = (a * sw[2 * j0] + b * sw[2 * j0 + 1]) + sbv[j0];
  float s1 = (a * sw[2 * j1] + b * sw[2 * j1 + 1]) + sbv[j1];
  sk[idx] = pk2(s0, s1);
}

// ---------------- qkvs layers 2..4 (Cin = 32): register tiles; q/skip packed bf16, kv packed bf16 ----------------
#define QP 36   // x pitch (floats)
#define WP 33   // W pitch (floats)
__global__ __launch_bounds__(256) void k_qkvs3(
    const float* __restrict__ yb, const float* __restrict__ stats,
    const float* __restrict__ bng, const float* __restrict__ bnb,
    const float* __restrict__ wq, const float* __restrict__ bq,
    const float* __restrict__ wk, const float* __restrict__ bk,
    const float* __restrict__ wv, const float* __restrict__ bv,
    const float* __restrict__ wsk, const float* __restrict__ bsk,
    unsigned* __restrict__ oq, unsigned short* __restrict__ okv, unsigned* __restrict__ osk)
{
  __shared__ __align__(16) float xs[64 * QP];
  __shared__ __align__(16) float Wl[2 * 128 * WP];

  const int t = threadIdx.x;
  const int nq = t & 15;
  const int chq = t >> 4;          // 0..15
  const int y = blockIdx.y;

  if (y == 1) {
    for (int idx = t; idx < 128 * 32; idx += 256) {
      int c = idx >> 5, k = idx & 31;
      Wl[c * WP + k] = wk[idx];
      Wl[128 * WP + c * WP + k] = wv[idx];
    }
  } else {
    const float* W = (y == 0) ? wq : wsk;
    for (int idx = t; idx < 128 * 32; idx += 256) {
      int c = idx >> 5, k = idx & 31;
      Wl[c * WP + k] = W[idx];
    }
  }

  const int ch0 = (t & 7) * 4;
  float sc[4], sh[4];
  #pragma unroll
  for (int c = 0; c < 4; ++c) {
    int ch = ch0 + c;
    float rsig = 1.0f / stats[32 + ch];
    sc[c] = bng[ch] * rsig;
    sh[c] = bnb[ch] - stats[ch] * sc[c];
  }

  const int ntiles = (NN + 63) / 64;
  for (int tile = blockIdx.x; tile < ntiles; tile += gridDim.x) {
    const int base = tile * 64;
    __syncthreads();
    #pragma unroll
    for (int rep = 0; rep < 2; ++rep) {
      int f = t + rep * 256;
      int n = f >> 3, kq = f & 7;
      int gn = base + n;
      if (gn >= NN) gn = NN - 1;
      float4 v = *(const float4*)(yb + (size_t)gn * 32 + kq * 4);
      v.x = fmaf(v.x, sc[0], sh[0]);
      v.y = fmaf(v.y, sc[1], sh[1]);
      v.z = fmaf(v.z, sc[2], sh[2]);
      v.w = fmaf(v.w, sc[3], sh[3]);
      *(float4*)(xs + n * QP + kq * 4) = v;
    }
    __syncthreads();

    if (y == 1) {
      float ak[4][8], av[4][8];
      #pragma unroll
      for (int s = 0; s < 4; ++s)
        #pragma unroll
        for (int j = 0; j < 8; ++j) { ak[s][j] = bk[chq * 8 + j]; av[s][j] = bv[chq * 8 + j]; }
      #pragma unroll 4
      for (int k2 = 0; k2 < 16; ++k2) {
        const int k = 2 * k2;
        float2 xv[4];
        #pragma unroll
        for (int s = 0; s < 4; ++s) xv[s] = *(const float2*)(xs + (nq + 16 * s) * QP + k);
        #pragma unroll
        for (int j = 0; j < 8; ++j) {
          float2 wk2 = *(const float2*)(Wl + (chq * 8 + j) * WP + k);
          float2 wv2 = *(const float2*)(Wl + 128 * WP + (chq * 8 + j) * WP + k);
          #pragma unroll
          for (int s = 0; s < 4; ++s) {
            ak[s][j] = fmaf(xv[s].x, wk2.x, ak[s][j]);
            ak[s][j] = fmaf(xv[s].y, wk2.y, ak[s][j]);
            av[s][j] = fmaf(xv[s].x, wv2.x, av[s][j]);
            av[s][j] = fmaf(xv[s].y, wv2.y, av[s][j]);
          }
        }
      }
      #pragma unroll
      for (int s = 0; s < 4; ++s) {
        int node = base + nq + 16 * s;
        if (node < NN) {
          uint4 A, B;
          A.x = pk2(ak[s][0], ak[s][1]); A.y = pk2(av[s][0], av[s][1]);
          A.z = pk2(ak[s][2], ak[s][3]); A.w = pk2(av[s][2], av[s][3]);
          B.x = pk2(ak[s][4], ak[s][5]); B.y = pk2(av[s][4], av[s][5]);
          B.z = pk2(ak[s][6], ak[s][7]); B.w = pk2(av[s][6], av[s][7]);
          unsigned short* dst = okv + (size_t)node * 256 + chq * 16;
          *(uint4*)dst = A;
          *(uint4*)(dst + 8) = B;
        }
      }
    } else {
      // y==0: q, y==2: skip — both packed bf16 (64 uints/node)
      const float* B = (y == 0) ? bq : bsk;
      unsigned* Of = (y == 0) ? oq : osk;
      float acc[4][8];
      #pragma unroll
      for (int s = 0; s < 4; ++s)
        #pragma unroll
        for (int j = 0; j < 8; ++j) acc[s][j] = B[chq * 8 + j];
      #pragma unroll 4
      for (int k2 = 0; k2 < 16; ++k2) {
        const int k = 2 * k2;
        float2 xv[4];
        #pragma unroll
        for (int s = 0; s < 4; ++s) xv[s] = *(const float2*)(xs + (nq + 16 * s) * QP + k);
        #pragma unroll
        for (int j = 0; j < 8; ++j) {
          float2 w2 = *(const float2*)(Wl + (chq * 8 + j) * WP + k);
          #pragma unroll
          for (int s = 0; s < 4; ++s) {
            acc[s][j] = fmaf(xv[s].x, w2.x, acc[s][j]);
            acc[s][j] = fmaf(xv[s].y, w2.y, acc[s][j]);
          }
        }
      }
      #pragma unroll
      for (int s = 0; s < 4; ++s) {
        int node = base + nq + 16 * s;
        if (node < NN) {
          uint4 Q;
          Q.x = pk2(acc[s][0], acc[s][1]);
          Q.y = pk2(acc[s][2], acc[s][3]);
          Q.z = pk2(acc[s][4], acc[s][5]);
          Q.w = pk2(acc[s][6], acc[s][7]);
          *(uint4*)(Of + (size_t)node * 64 + chq * 4) = Q;
        }
      }
    }
  }
}

// lin1: relu(BN(yb) @ W^T + b) -> 128 packed bf16
__global__ __launch_bounds__(256) void k_lin1d(
    const float* __restrict__ yb, const float* __restrict__ stats,
    const float* __restrict__ bng, const float* __restrict__ bnb,
    const float* __restrict__ W, const float* __restrict__ B, unsigned* __restrict__ O)
{
  __shared__ __align__(16) float xs[64 * QP];
  __shared__ __align__(16) float Wl[128 * WP];
  const int t = threadIdx.x;
  const int nq = t & 15;
  const int chq = t >> 4;
  for (int idx = t; idx < 128 * 32; idx += 256) {
    int c = idx >> 5, k = idx & 31;
    Wl[c * WP + k] = W[idx];
  }
  const int ch0 = (t & 7) * 4;
  float sc[4], sh[4];
  #pragma unroll
  for (int c = 0; c < 4; ++c) {
    int ch = ch0 + c;
    float rsig = 1.0f / stats[32 + ch];
    sc[c] = bng[ch] * rsig;
    sh[c] = bnb[ch] - stats[ch] * sc[c];
  }
  const int ntiles = (NN + 63) / 64;
  for (int tile = blockIdx.x; tile < ntiles; tile += gridDim.x) {
    const int base = tile * 64;
    __syncthreads();
    #pragma unroll
    for (int rep = 0; rep < 2; ++rep) {
      int f = t + rep * 256;
      int n = f >> 3, kq = f & 7;
      int gn = base + n;
      if (gn >= NN) gn = NN - 1;
      float4 v = *(const float4*)(yb + (size_t)gn * 32 + kq * 4);
      v.x = fmaf(v.x, sc[0], sh[0]);
      v.y = fmaf(v.y, sc[1], sh[1]);
      v.z = fmaf(v.z, sc[2], sh[2]);
      v.w = fmaf(v.w, sc[3], sh[3]);
      *(float4*)(xs + n * QP + kq * 4) = v;
    }
    __syncthreads();
    float acc[4][8];
    #pragma unroll
    for (int s = 0; s < 4; ++s)
      #pragma unroll
      for (int j = 0; j < 8; ++j) acc[s][j] = B[chq * 8 + j];
    #pragma unroll 4
    for (int k2 = 0; k2 < 16; ++k2) {
      const int k = 2 * k2;
      float2 xv[4];
      #pragma unroll
      for (int s = 0; s < 4; ++s) xv[s] = *(const float2*)(xs + (nq + 16 * s) * QP + k);
      #pragma unroll
      for (int j = 0; j < 8; ++j) {
        float2 w2 = *(const float2*)(Wl + (chq * 8 + j) * WP + k);
        #pragma unroll
        for (int s = 0; s < 4; ++s) {
          acc[s][j] = fmaf(xv[s].x, w2.x, acc[s][j]);
          acc[s][j] = fmaf(xv[s].y, w2.y, acc[s][j]);
        }
      }
    }
    #pragma unroll
    for (int s = 0; s < 4; ++s) {
      int node = base + nq + 16 * s;
      if (node < NN) {
        uint4 P;
        P.x = pk2(fmaxf(acc[s][0], 0.f), fmaxf(acc[s][1], 0.f));
        P.y = pk2(fmaxf(acc[s][2], 0.f), fmaxf(acc[s][3], 0.f));
        P.z = pk2(fmaxf(acc[s][4], 0.f), fmaxf(acc[s][5], 0.f));
        P.w = pk2(fmaxf(acc[s][6], 0.f), fmaxf(acc[s][7], 0.f));
        *(uint4*)(O + (size_t)node * 64 + chq * 4) = P;
      }
    }
  }
}

// ---------------- k_dense: packed-bf16 [NN x 128] @ W^T[128 x COUT] + relu ----------------
#define XPITCH 132
#define WPITCH 130
template<int COUT, bool STATS, bool REM>
__global__ __launch_bounds__(256) void k_dense(
    const unsigned* __restrict__ xin, const float* __restrict__ W,
    const float* __restrict__ bias, float* __restrict__ out,
    double* __restrict__ psum, double* __restrict__ psq,
    const float* __restrict__ rw, const float* __restrict__ rb,
    const float* __restrict__ amask, float* __restrict__ rl)
{
  constexpr int JB = COUT / 16;   // channels per thread
  __shared__ __align__(16) float xs[64 * XPITCH];
  __shared__ float Ws[COUT * WPITCH];
  __shared__ float rem_lds[REM ? 16 * 64 : 1];

  const int t = threadIdx.x;
  const int nq = t & 15;
  const int chq = t >> 4;

  for (int idx = t; idx < COUT * 128; idx += 256) {
    int c = idx >> 7, k = idx & 127;
    Ws[c * WPITCH + k] = W[idx];
  }
  float bj[JB];
  float rwj[REM ? JB : 1];
  #pragma unroll
  for (int j = 0; j < JB; ++j) {
    bj[j] = bias[chq * JB + j];
    if (REM) rwj[j] = rw[chq * JB + j];
  }
  double sd[STATS ? JB : 1], sq[STATS ? JB : 1];
  if (STATS) {
    #pragma unroll
    for (int j = 0; j < JB; ++j) { sd[j] = 0.0; sq[j] = 0.0; }
  }

  const uint4* xin4 = (const uint4*)xin;
  const int ntiles = (NN + 63) / 64;
  for (int tile = blockIdx.x; tile < ntiles; tile += gridDim.x) {
    const int base = tile * 64;
    __syncthreads();
    // stage: 64 nodes x 16 uint4 (128 bf16 each) -> f32 LDS tile
    #pragma unroll
    for (int r = 0; r < 4; ++r) {
      int f = t + r * 256;              // 1024 uint4 slots
      int n = f >> 4, kq = f & 15;
      int gn = base + n;
      if (gn >= NN) gn = NN - 1;
      uint4 v = xin4[(size_t)gn * 16 + kq];
      float* d = xs + n * XPITCH + kq * 8;
      float4 lo, hi;
      lo.x = bf2f(LO16(v.x)); lo.y = bf2f(HI16(v.x));
      lo.z = bf2f(LO16(v.y)); lo.w = bf2f(HI16(v.y));
      hi.x = bf2f(LO16(v.z)); hi.y = bf2f(HI16(v.z));
      hi.z = bf2f(LO16(v.w)); hi.w = bf2f(HI16(v.w));
      *(float4*)d = lo;
      *(float4*)(d + 4) = hi;
    }
    __syncthreads();

    float acc[4][JB];
    #pragma unroll
    for (int s = 0; s < 4; ++s)
      #pragma unroll
      for (int j = 0; j < JB; ++j) acc[s][j] = bj[j];

    #pragma unroll 8
    for (int k2 = 0; k2 < 64; ++k2) {
      const int k = 2 * k2;
      float2 xv[4];
      #pragma unroll
      for (int s = 0; s < 4; ++s)
        xv[s] = *(const float2*)(xs + (nq + 16 * s) * XPITCH + k);
      float2 wv[JB];
      #pragma unroll
      for (int j = 0; j < JB; ++j)
        wv[j] = *(const float2*)(Ws + (chq * JB + j) * WPITCH + k);
      #pragma unroll
      for (int s = 0; s < 4; ++s)
        #pragma unroll
        for (int j = 0; j < JB; ++j) {
          acc[s][j] = fmaf(xv[s].x, wv[j].x, acc[s][j]);
          acc[s][j] = fmaf(xv[s].y, wv[j].y, acc[s][j]);
        }
    }

    #pragma unroll
    for (int s = 0; s < 4; ++s) {
      const int node = base + nq + 16 * s;
      const bool ok = node < NN;
      #pragma unroll
      for (int j = 0; j < JB; ++j) acc[s][j] = fmaxf(acc[s][j], 0.f);
      if (ok) {
        if (COUT == 32) {
          *(float2*)(out + (size_t)node * 32 + chq * 2) = make_float2(acc[s][0], acc[s][1]);
        } else {
          *(float4*)(out + (size_t)node * 64 + chq * 4) =
              make_float4(acc[s][0], acc[s][1], acc[s][2], acc[s][3]);
        }
      }
      if (STATS && ok) {
        #pragma unroll
        for (int j = 0; j < JB; ++j) {
          sd[j] += (double)acc[s][j];
          sq[j] += (double)acc[s][j] * (double)acc[s][j];
        }
      }
      if (REM) {
        float p = 0.f;
        #pragma unroll
        for (int j = 0; j < JB; ++j) p = fmaf(acc[s][j], rwj[j], p);
        rem_lds[chq * 64 + nq + 16 * s] = p;
      }
    }

    if (REM) {
      __syncthreads();
      if (t < 64) {
        int node = base + t;
        if (node < NN) {
          float v = rb[0];
          #pragma unroll
          for (int c = 0; c < 16; ++c) v += rem_lds[c * 64 + t];
          float mv = amask[node];
          float mterm;
          if (node < 15) mterm = (mv == 0.f) ? -INFINITY : ((mv == -INFINITY) ? 0.f : mv);
          else mterm = mv;
          rl[node] = fmaxf(v + mterm, NEGBIG);
        }
      }
    }
  }

  if (STATS) {
    __shared__ double sred[256 * 2];
    __syncthreads();
    #pragma unroll
    for (int j = 0; j < JB; ++j) { sred[t * 2 + j] = sd[j]; }
    __syncthreads();
    if (t < 32) {
      int cq = t >> 1, j = t & 1;
      double a = 0.0;
      #pragma unroll
      for (int n = 0; n < 16; ++n) a += sred[(cq * 16 + n) * 2 + j];
      psum[blockIdx.x * 32 + t] = a;
    }
    __syncthreads();
    #pragma unroll
    for (int j = 0; j < JB; ++j) { sred[t * 2 + j] = sq[j]; }
    __syncthreads();
    if (t < 32) {
      int cq = t >> 1, j = t & 1;
      double a = 0.0;
      #pragma unroll
      for (int n = 0; n < 16; ++n) a += sred[(cq * 16 + n) * 2 + j];
      psq[blockIdx.x * 32 + t] = a;
    }
  }
}

// parallel BN-stats finalize over NDB partials
__global__ __launch_bounds__(1024) void k_stats2(
    const double* __restrict__ psum, const double* __restrict__ psq, float* __restrict__ stats)
{
  const int t = threadIdx.x;
  const int ch = t & 31;
  const int chunk = t >> 5;
  double s = 0.0, q = 0.0;
  for (int b = chunk; b < NDB; b += 32) { s += psum[b * 32 + ch]; q += psq[b * 32 + ch]; }
  __shared__ double rs[1024];
  __shared__ double rq[1024];
  rs[t] = s; rq[t] = q;
  __syncthreads();
  for (int off = 16; off > 0; off >>= 1) {
    if (chunk < off) { rs[t] += rs[t + off * 32]; rq[t] += rq[t + off * 32]; }
    __syncthreads();
  }
  if (t < 32) {
    double mu = rs[t] / (double)NN;
    double var = rq[t] / (double)NN - mu * mu;
    if (var < 0.0) var = 0.0;
    stats[t] = (float)mu;
    stats[32 + t] = sqrtf((float)var + 1e-5f);
  }
}

// ---------------- attention: wave = one dst node, 2 edges/wave-step ----------------
// Lanes 0-31 process even edges, 32-63 odd edges. Each lane holds 4 channels
// (jl = lane&31 -> channels 4jl..4jl+3); 8-lane head groups; reduce xor 1,2,4.
__global__ __launch_bounds__(256) void k_attn(
    const unsigned* __restrict__ qb, const unsigned short* __restrict__ kvb,
    unsigned* __restrict__ skh,
    const int* __restrict__ rowptr, const int2* __restrict__ csr,
    const float* __restrict__ ew, const float* __restrict__ bw)
{
  const int wid = (blockIdx.x * 256 + threadIdx.x) >> 6;
  const int lane = threadIdx.x & 63;
  const int jl = lane & 31;
  const int hf = lane >> 5;
  if (wid >= NN) return;

  // q channels 4jl..4jl+3
  uint2 qu = *(const uint2*)(qb + (size_t)wid * 64 + 2 * jl);
  const float q0 = bf2f(LO16(qu.x)), q1 = bf2f(HI16(qu.x));
  const float q2 = bf2f(LO16(qu.y)), q3 = bf2f(HI16(qu.y));
  float4 ew4 = *(const float4*)(ew + 4 * jl);
  const uint4* kvp4 = (const uint4*)kvb;   // 32 uint4 per node row
  const int p0 = rowptr[wid], p1 = rowptr[wid + 1];

  float s = 0.f, a0 = 0.f, a1 = 0.f, a2 = 0.f, a3 = 0.f;
  const float iscale = 0.17677669529663689f;  // 1/sqrt(32)

#define STEP(c, kv) {                                                   \
    float lat = __int_as_float((c).y);                                  \
    float e0 = lat * ew4.x, e1 = lat * ew4.y;                           \
    float e2 = lat * ew4.z, e3 = lat * ew4.w;                           \
    float part = (bf2f(LO16((kv).x)) + e0) * q0                         \
               + (bf2f(HI16((kv).x)) + e1) * q1                         \
               + (bf2f(LO16((kv).z)) + e2) * q2                         \
               + (bf2f(HI16((kv).z)) + e3) * q3;                        \
    part += __shfl_xor(part, 1);                                        \
    part += __shfl_xor(part, 2);                                        \
    part += __shfl_xor(part, 4);                                        \
    float pt = __expf(part * iscale);                                   \
    s += pt;                                                            \
    a0 = fmaf(pt, bf2f(LO16((kv).y)) + e0, a0);                         \
    a1 = fmaf(pt, bf2f(HI16((kv).y)) + e1, a1);                         \
    a2 = fmaf(pt, bf2f(LO16((kv).w)) + e2, a2);                         \
    a3 = fmaf(pt, bf2f(HI16((kv).w)) + e3, a3); }

#define STEPV(c, kv, vf) {                                              \
    float lat = __int_as_float((c).y);                                  \
    float e0 = lat * ew4.x, e1 = lat * ew4.y;                           \
    float e2 = lat * ew4.z, e3 = lat * ew4.w;                           \
    float part = (bf2f(LO16((kv).x)) + e0) * q0                         \
               + (bf2f(HI16((kv).x)) + e1) * q1                         \
               + (bf2f(LO16((kv).z)) + e2) * q2                         \
               + (bf2f(HI16((kv).z)) + e3) * q3;                        \
    part += __shfl_xor(part, 1);                                        \
    part += __shfl_xor(part, 2);                                        \
    part += __shfl_xor(part, 4);                                        \
    float pt = __expf(part * iscale) * (vf);                            \
    s += pt;                                                            \
    a0 = fmaf(pt, bf2f(LO16((kv).y)) + e0, a0);                         \
    a1 = fmaf(pt, bf2f(HI16((kv).y)) + e1, a1);                         \
    a2 = fmaf(pt, bf2f(LO16((kv).w)) + e2, a2);                         \
    a3 = fmaf(pt, bf2f(HI16((kv).w)) + e3, a3); }

  int p = p0;
  // main: 8 edges per iteration (4 two-edge steps), all valid
  for (; p + 7 < p1; p += 8) {
    int2 c0 = csr[p + hf];
    int2 c1 = csr[p + 2 + hf];
    int2 c2 = csr[p + 4 + hf];
    int2 c3 = csr[p + 6 + hf];
    uint4 kv0 = kvp4[(size_t)c0.x * 32 + jl];
    uint4 kv1 = kvp4[(size_t)c1.x * 32 + jl];
    uint4 kv2 = kvp4[(size_t)c2.x * 32 + jl];
    uint4 kv3 = kvp4[(size_t)c3.x * 32 + jl];
    STEP(c0, kv0)
    STEP(c1, kv1)
    STEP(c2, kv2)
    STEP(c3, kv3)
  }
  // remainder: 2 edges per step with validity mask
  for (; p < p1; p += 2) {
    int ei = p + hf;
    int pe = (ei < p1) ? ei : p;
    float vf = (ei < p1) ? 1.f : 0.f;
    int2 c = csr[pe];
    uint4 kv = kvp4[(size_t)c.x * 32 + jl];
    STEPV(c, kv, vf)
  }
#undef STEP
#undef STEPV

  // combine halves (even/odd edge partitions)
  s  += __shfl_xor(s, 32);
  a0 += __shfl_xor(a0, 32);
  a1 += __shfl_xor(a1, 32);
  a2 += __shfl_xor(a2, 32);
  a3 += __shfl_xor(a3, 32);

  float inv = (s > 0.f) ? (1.0f / s) : 1.0f;
  float o0 = a0 * inv, o1 = a1 * inv, o2 = a2 * inv, o3 = a3 * inv;

  uint2 su = *(const uint2*)(skh + (size_t)wid * 64 + 2 * jl);
  float sk0 = bf2f(LO16(su.x)), sk1 = bf2f(HI16(su.x));
  float sk2 = bf2f(LO16(su.y)), sk3 = bf2f(HI16(su.y));
  float4 b1 = *(const float4*)(bw + 4 * jl);
  float4 b2 = *(const float4*)(bw + 128 + 4 * jl);
  float4 b3 = *(const float4*)(bw + 256 + 4 * jl);
  float part = b1.x * o0 + b1.y * o1 + b1.z * o2 + b1.w * o3
             + b2.x * sk0 + b2.y * sk1 + b2.z * sk2 + b2.w * sk3
             + b3.x * (o0 - sk0) + b3.y * (o1 - sk1)
             + b3.z * (o2 - sk2) + b3.w * (o3 - sk3);
  part += __shfl_xor(part, 1);
  part += __shfl_xor(part, 2);
  part += __shfl_xor(part, 4);
  part += __shfl_xor(part, 8);
  part += __shfl_xor(part, 16);          // full dot within each 32-lane half
  float beta = 1.f / (1.f + __expf(-part));
  float h0 = beta * sk0 + (1.f - beta) * o0;
  float h1 = beta * sk1 + (1.f - beta) * o1;
  float h2 = beta * sk2 + (1.f - beta) * o2;
  float h3 = beta * sk3 + (1.f - beta) * o3;
  if (hf == 0)
    *(uint2*)(skh + (size_t)wid * 64 + 2 * jl) = make_uint2(pk2(h0, h1), pk2(h2, h3));
}

// ---------------- sampling machinery ----------------
__global__ __launch_bounds__(256) void k_pass(
    const float* __restrict__ lg,
    float* __restrict__ pm, float* __restrict__ ps, float* __restrict__ pg, int* __restrict__ pidx,
    unsigned ka, unsigned kb)
{
  float m = -INFINITY, s = 0.f, g = -INFINITY; int gi = INT_MAX; bool hg = false;
  for (int i = blockIdx.x * 256 + threadIdx.x; i < NN; i += gridDim.x * 256) {
    float v = lg[i];
    if (v > m) { s = (m == -INFINITY) ? 1.f : fmaf(s, expf(m - v), 1.f); m = v; }
    else if (v != -INFINITY) s += expf(v - m);
    float tot = v + gumbel_of(ka, kb, i);
    if (!hg || tot > g || (tot == g && i < gi)) { g = tot; gi = i; hg = true; }
  }
  __shared__ float sm[256], ss[256], sg[256]; __shared__ int si[256];
  int t = threadIdx.x;
  sm[t] = m; ss[t] = s; sg[t] = g; si[t] = gi;
  __syncthreads();
  for (int off = 128; off > 0; off >>= 1) {
    if (t < off) {
      float m2 = sm[t + off], s2 = ss[t + off];
      float M = fmaxf(sm[t], m2);
      float sn = 0.f;
      if (M != -INFINITY) {
        if (sm[t] != -INFINITY) sn += ss[t] * expf(sm[t] - M);
        if (m2 != -INFINITY) sn += s2 * expf(m2 - M);
      }
      sm[t] = M; ss[t] = sn;
      float g2 = sg[t + off]; int i2 = si[t + off];
      if (g2 > sg[t] || (g2 == sg[t] && i2 < si[t])) { sg[t] = g2; si[t] = i2; }
    }
    __syncthreads();
  }
  if (t == 0) { pm[blockIdx.x] = sm[0]; ps[blockIdx.x] = ss[0]; pg[blockIdx.x] = sg[0]; pidx[blockIdx.x] = si[0]; }
}

// choose + optional fused proj (aw != nullptr only for the first draw)
__global__ __launch_bounds__(PB) void k_choose(
    const float* __restrict__ lg,
    const float* __restrict__ pm, const float* __restrict__ ps,
    const float* __restrict__ pg, const int* __restrict__ pidx,
    float* __restrict__ act_out, float* __restrict__ lp_out, int* __restrict__ a_scr,
    const float* __restrict__ xf, const float* __restrict__ aw,
    const float* __restrict__ ab, float* __restrict__ proj)
{
  __shared__ float sm[PB], ss[PB], sg[PB]; __shared__ int si[PB];
  __shared__ float xs2[64];
  int t = threadIdx.x;
  sm[t] = pm[t]; ss[t] = ps[t]; sg[t] = pg[t]; si[t] = pidx[t];
  __syncthreads();
  for (int off = PB / 2; off > 0; off >>= 1) {
    if (t < off) {
      float m2 = sm[t + off], s2 = ss[t + off];
      float M = fmaxf(sm[t], m2);
      float sn = 0.f;
      if (M != -INFINITY) {
        if (sm[t] != -INFINITY) sn += ss[t] * expf(sm[t] - M);
        if (m2 != -INFINITY) sn += s2 * expf(m2 - M);
      }
      sm[t] = M; ss[t] = sn;
      float g2 = sg[t + off]; int i2 = si[t + off];
      if (g2 > sg[t] || (g2 == sg[t] && i2 < si[t])) { sg[t] = g2; si[t] = i2; }
    }
    __syncthreads();
  }
  if (t == 0) {
    int a = si[0];
    a_scr[0] = a;
    act_out[0] = (float)a;
    lp_out[0] = (lg[a] - sm[0]) - logf(ss[0]);
  }
  if (aw != nullptr) {
    __syncthreads();
    int a = si[0];
    if (t < 64) xs2[t] = xf[(size_t)a * 64 + t];
    __syncthreads();
    if (t < 64) {
      float acc = 0.f;
      #pragma unroll
      for (int i = 0; i < 64; ++i) acc = fmaf(xs2[i], aw[t * 64 + i], acc);
      proj[t] = tanhf(acc + ab[t]);
    }
  }
}

__global__ __launch_bounds__(256) void k_nl(
    const float* __restrict__ xf, const float* __restrict__ proj,
    const float* __restrict__ amask, const int* __restrict__ a1p, float* __restrict__ nl)
{
  int wid = (blockIdx.x * 256 + threadIdx.x) >> 6;
  int lane = threadIdx.x & 63;
  if (wid >= NN) return;
  float part = xf[(size_t)wid * 64 + lane] * proj[lane];
  #pragma unroll
  for (int off = 1; off < 64; off <<= 1) part += __shfl_xor(part, off);
  if (lane == 0) {
    int a1 = a1p[0];
    float mv = (wid == a1) ? 0.f : amask[wid];
    nl[wid] = fmaxf(part + mv, NEGBIG);
  }
}

// ---------------- host ----------------
extern "C" void kernel_launch(void* const* d_in, const int* in_sizes, int n_in,
                              void* d_out, int out_size, void* d_ws, size_t ws_size,
                              hipStream_t stream)
{
  (void)in_sizes; (void)n_in; (void)out_size; (void)ws_size;

  const float* node_type = (const float*)d_in[0];
  const float* requests  = (const float*)d_in[1];
  const float* latency   = (const float*)d_in[2];
  const float* amask     = (const float*)d_in[3];
  const int*   eidx      = (const int*)d_in[4];
  const int* esrc = eidx;
  const int* edst = eidx + NE;

  const float* q1_w = (const float*)d_in[5];  const float* q1_b = (const float*)d_in[6];
  const float* k1_w = (const float*)d_in[7];  const float* k1_b = (const float*)d_in[8];
  const float* v1_w = (const float*)d_in[9];  const float* v1_b = (const float*)d_in[10];
  const float* e1_w = (const float*)d_in[11];
  const float* sk1_w = (const float*)d_in[12]; const float* sk1_b = (const float*)d_in[13];
  const float* be1_w = (const float*)d_in[14];
  const float* tf1_w = (const float*)d_in[15]; const float* tf1_b = (const float*)d_in[16];
  const float* bn1_g = (const float*)d_in[17]; const float* bn1_b = (const float*)d_in[18];
  const float* qL_w = (const float*)d_in[19]; const float* qL_b = (const float*)d_in[20];
  const float* kL_w = (const float*)d_in[21]; const float* kL_b = (const float*)d_in[22];
  const float* vL_w = (const float*)d_in[23]; const float* vL_b = (const float*)d_in[24];
  const float* eL_w = (const float*)d_in[25];
  const float* skL_w = (const float*)d_in[26]; const float* skL_b = (const float*)d_in[27];
  const float* beL_w = (const float*)d_in[28];
  const float* tfL_w = (const float*)d_in[29]; const float* tfL_b = (const float*)d_in[30];
  const float* bnL_g = (const float*)d_in[31]; const float* bnL_b = (const float*)d_in[32];
  const float* l1_w = (const float*)d_in[33]; const float* l1_b = (const float*)d_in[34];
  const float* l2_w = (const float*)d_in[35]; const float* l2_b = (const float*)d_in[36];
  const float* rem_w = (const float*)d_in[37]; const float* rem_b = (const float*)d_in[38];
  const float* ap_w = (const float*)d_in[39]; const float* ap_b = (const float*)d_in[40];

  // workspace layout (~130 MB)
  char* ws = (char*)d_ws;
  size_t off = 0;
  auto alloc = [&](size_t bytes) -> void* {
    void* p = ws + off;
    off += (bytes + 255) & ~(size_t)255;
    return p;
  };
  unsigned* qbuf = (unsigned*)alloc((size_t)NN * 64 * 4);                // packed q bf16
  unsigned short* kvbuf = (unsigned short*)alloc((size_t)NN * 256 * 2);  // packed k,v bf16
  unsigned* skb = (unsigned*)alloc((size_t)NN * 64 * 4);  // packed skip in / h out (bf16)
  float* yb   = (float*)alloc((size_t)NN * 32 * 4);       // relu(transf) pre-BN (f32)
  int*   rowptr = (int*)alloc((size_t)(NN + 1) * 4);
  int*   deg    = (int*)alloc((size_t)NN * 4);
  int*   fill   = (int*)alloc((size_t)NN * 4);
  int2*  csr    = (int2*)alloc((size_t)NE * 8);           // packed (src, lat)
  double* psum = (double*)alloc((size_t)NDB * 32 * 8);
  double* psq  = (double*)alloc((size_t)NDB * 32 * 8);
  float* stats = (float*)alloc(64 * 4);
  float* pm = (float*)alloc(PB * 4);
  float* ps = (float*)alloc(PB * 4);
  float* pg = (float*)alloc(PB * 4);
  int*   pidx = (int*)alloc(PB * 4);
  float* proj = (float*)alloc(64 * 4);
  int*   a_scr = (int*)alloc(2 * 4);
  unsigned* y1 = skb;         // lin1 output (packed bf16) reuses skb
  float* xf = (float*)kvbuf;  // lin2 output (f32) reuses kv buffer

  // JAX PRNG: key(42) -> foldlike split -> (k1, k2)
  unsigned k1a, k1b, k2a, k2b;
  tf_host(0u, 42u, 0u, 0u, &k1a, &k1b);
  tf_host(0u, 42u, 0u, 1u, &k2a, &k2b);

  float* dout = (float*)d_out;

  // CSR build (reused by all 4 conv layers)
  k_zero2<<<(NN + 255) / 256, 256, 0, stream>>>(deg, fill);
  k_hist<<<(NE + 255) / 256, 256, 0, stream>>>(edst, deg);
  k_scan<<<1, 1024, 0, stream>>>(deg, rowptr);
  k_scatter<<<(NE + 255) / 256, 256, 0, stream>>>(esrc, edst, latency, rowptr, fill, csr);

  // ---- conv layer 1 (Cin=2) ----
  k_qkvs_first<<<(NN * 64 + 255) / 256, 256, 0, stream>>>(
      node_type, requests, q1_w, q1_b, k1_w, k1_b, v1_w, v1_b, sk1_w, sk1_b,
      qbuf, kvbuf, skb);
  k_attn<<<NN / 4, 256, 0, stream>>>(qbuf, kvbuf, skb, rowptr, csr, e1_w, be1_w);
  k_dense<32, true, false><<<NDB, 256, 0, stream>>>(skb, tf1_w, tf1_b, yb, psum, psq,
                                                    nullptr, nullptr, nullptr, nullptr);
  k_stats2<<<1, 1024, 0, stream>>>(psum, psq, stats);

  // ---- conv layers 2..4 (Cin=32), BN of previous layer fused into qkvs load ----
  for (int i = 0; i < 3; ++i) {
    const float* g = (i == 0) ? bn1_g : bnL_g + (i - 1) * 32;
    const float* b = (i == 0) ? bn1_b : bnL_b + (i - 1) * 32;
    k_qkvs3<<<dim3(NDB, 3), 256, 0, stream>>>(
        yb, stats, g, b,
        qL_w + i * 4096, qL_b + i * 128,
        kL_w + i * 4096, kL_b + i * 128,
        vL_w + i * 4096, vL_b + i * 128,
        skL_w + i * 4096, skL_b + i * 128,
        qbuf, kvbuf, skb);
    k_attn<<<NN / 4, 256, 0, stream>>>(qbuf, kvbuf, skb, rowptr, csr,
                                       eL_w + i * 128, beL_w + i * 384);
    k_dense<32, true, false><<<NDB, 256, 0, stream>>>(skb, tfL_w + i * 4096, tfL_b + i * 32,
                                                      yb, psum, psq,
                                                      nullptr, nullptr, nullptr, nullptr);
    k_stats2<<<1, 1024, 0, stream>>>(psum, psq, stats);
  }

  // ---- MLP (BN of layer-4 fused into lin1 load); rem head fused into lin2 ----
  k_lin1d<<<NDB, 256, 0, stream>>>(yb, stats, bnL_g + 2 * 32, bnL_b + 2 * 32, l1_w, l1_b, y1);
  k_dense<64, false, true><<<NDB, 256, 0, stream>>>(y1, l2_w, l2_b, xf, nullptr, nullptr,
                                                    rem_w, rem_b, amask, dout);

  // ---- sampling ----
  k_pass<<<PB, 256, 0, stream>>>(dout, pm, ps, pg, pidx, k1a, k1b);
  k_choose<<<1, PB, 0, stream>>>(dout, pm, ps, pg, pidx,
                                 dout + 2 * NN, dout + 2 * NN + 2, a_scr,
                                 xf, ap_w, ap_b, proj);
  k_nl<<<NN / 4, 256, 0, stream>>>(xf, proj, amask, a_scr, dout + NN);
  k_pass<<<PB, 256, 0, stream>>>(dout + NN, pm, ps, pg, pidx, k2a, k2b);
  k_choose<<<1, PB, 0, stream>>>(dout + NN, pm, ps, pg, pidx,
                                 dout + 2 * NN + 1, dout + 2 * NN + 3, a_scr + 1,
                                 nullptr, nullptr, nullptr, nullptr);
}

// Round 14
// 831.246 us; speedup vs baseline: 1.0767x; 1.0767x over previous
//
#include <hip/hip_runtime.h>
#include <hip/hip_bf16.h>
#include <math.h>
#include <stdint.h>
#include <limits.h>

#define NN 100000
#define NE 800000
#define PB 512                    // blocks for argmax/lse partial reduction
#define NDB 512                   // blocks for k_dense (BN-stat partials)
#define NEGBIG (-1e30f)

typedef __hip_bfloat16 bf16;

__device__ __forceinline__ float bf2f(unsigned short u)
{
  union { unsigned v; float f; } x; x.v = ((unsigned)u) << 16; return x.f;
}
__device__ __forceinline__ unsigned short f2bf(float f)
{
  bf16 h = __float2bfloat16(f);
  return *reinterpret_cast<unsigned short*>(&h);
}
__device__ __forceinline__ unsigned pk2(float a, float b)
{
  return (unsigned)f2bf(a) | ((unsigned)f2bf(b) << 16);
}
#define LO16(u) ((unsigned short)((u) & 0xffffu))
#define HI16(u) ((unsigned short)((u) >> 16))

// ---------------- threefry2x32-20 (JAX PRNG) ----------------
__device__ __forceinline__ uint2 tf_dev(unsigned k0, unsigned k1, unsigned x0, unsigned x1)
{
  const unsigned ks2 = k0 ^ k1 ^ 0x1BD11BDAu;
#define TFR(r) { x0 += x1; x1 = (x1 << r) | (x1 >> (32 - r)); x1 ^= x0; }
  x0 += k0; x1 += k1;
  TFR(13) TFR(15) TFR(26) TFR(6)
  x0 += k1; x1 += ks2 + 1u;
  TFR(17) TFR(29) TFR(16) TFR(24)
  x0 += ks2; x1 += k0 + 2u;
  TFR(13) TFR(15) TFR(26) TFR(6)
  x0 += k0; x1 += k1 + 3u;
  TFR(17) TFR(29) TFR(16) TFR(24)
  x0 += k1; x1 += ks2 + 4u;
  TFR(13) TFR(15) TFR(26) TFR(6)
  x0 += ks2; x1 += k0 + 5u;
#undef TFR
  return make_uint2(x0, x1);
}

static void tf_host(unsigned k0, unsigned k1, unsigned x0, unsigned x1,
                    unsigned* o0, unsigned* o1)
{
  const unsigned ks2 = k0 ^ k1 ^ 0x1BD11BDAu;
#define TFR(r) { x0 += x1; x1 = (x1 << r) | (x1 >> (32 - r)); x1 ^= x0; }
  x0 += k0; x1 += k1;
  TFR(13) TFR(15) TFR(26) TFR(6)
  x0 += k1; x1 += ks2 + 1u;
  TFR(17) TFR(29) TFR(16) TFR(24)
  x0 += ks2; x1 += k0 + 2u;
  TFR(13) TFR(15) TFR(26) TFR(6)
  x0 += k0; x1 += k1 + 3u;
  TFR(17) TFR(29) TFR(16) TFR(24)
  x0 += k1; x1 += ks2 + 4u;
  TFR(13) TFR(15) TFR(26) TFR(6)
  x0 += ks2; x1 += k0 + 5u;
#undef TFR
  *o0 = x0; *o1 = x1;
}

__device__ __forceinline__ float gumbel_of(unsigned ka, unsigned kb, int i)
{
  uint2 c = tf_dev(ka, kb, 0u, (unsigned)i);
  unsigned bits = c.x ^ c.y;
  float f = __uint_as_float((bits >> 9) | 0x3f800000u) - 1.0f;
  const float TINYF = 1.17549435e-38f;
  float u = fmaxf(TINYF, f + TINYF);
  return -logf(-logf(u));
}

// ---------------- CSR build ----------------
__global__ __launch_bounds__(256) void k_zero2(int* __restrict__ a, int* __restrict__ b)
{
  int i = blockIdx.x * 256 + threadIdx.x;
  if (i < NN) { a[i] = 0; b[i] = 0; }
}

__global__ __launch_bounds__(256) void k_hist(const int* __restrict__ edst, int* __restrict__ deg)
{
  int e = blockIdx.x * 256 + threadIdx.x;
  if (e < NE) atomicAdd(&deg[edst[e]], 1);
}

__global__ __launch_bounds__(1024) void k_scan(const int* __restrict__ deg, int* __restrict__ rowptr)
{
  __shared__ int wsum[16];
  __shared__ int chtot;
  const int t = threadIdx.x;
  const int lane = t & 63;
  const int wv = t >> 6;
  int carry = 0;
  for (int base = 0; base < NN; base += 4096) {
    int i0 = base + t * 4;
    int d0 = 0, d1 = 0, d2 = 0, d3 = 0;
    if (i0 + 3 < NN) { int4 dd = *(const int4*)(deg + i0); d0 = dd.x; d1 = dd.y; d2 = dd.z; d3 = dd.w; }
    else {
      if (i0     < NN) d0 = deg[i0];
      if (i0 + 1 < NN) d1 = deg[i0 + 1];
      if (i0 + 2 < NN) d2 = deg[i0 + 2];
      if (i0 + 3 < NN) d3 = deg[i0 + 3];
    }
    int tsum = d0 + d1 + d2 + d3;
    int sc = tsum;
    #pragma unroll
    for (int off = 1; off < 64; off <<= 1) { int o = __shfl_up(sc, off); if (lane >= off) sc += o; }
    if (lane == 63) wsum[wv] = sc;
    __syncthreads();
    if (wv == 0 && lane < 16) {
      int wval = wsum[lane];
      int wsc = wval;
      #pragma unroll
      for (int off = 1; off < 16; off <<= 1) { int o = __shfl_up(wsc, off); if (lane >= off) wsc += o; }
      if (lane == 15) chtot = wsc;
      wsum[lane] = wsc - wval;  // exclusive
    }
    __syncthreads();
    int excl = carry + wsum[wv] + (sc - tsum);
    if (i0     < NN) rowptr[i0]     = excl;
    if (i0 + 1 < NN) rowptr[i0 + 1] = excl + d0;
    if (i0 + 2 < NN) rowptr[i0 + 2] = excl + d0 + d1;
    if (i0 + 3 < NN) rowptr[i0 + 3] = excl + d0 + d1 + d2;
    carry += chtot;
    __syncthreads();
  }
  if (t == 0) rowptr[NN] = carry;
}

__global__ __launch_bounds__(256) void k_scatter(
    const int* __restrict__ esrc, const int* __restrict__ edst,
    const float* __restrict__ lat, const int* __restrict__ rowptr,
    int* __restrict__ fill, int2* __restrict__ csr)
{
  int e = blockIdx.x * 256 + threadIdx.x;
  if (e >= NE) return;
  int d = edst[e];
  int pos = rowptr[d] + atomicAdd(&fill[d], 1);
  csr[pos] = make_int2(esrc[e], __float_as_int(lat[e]));
}

// ---------------- layer 1 q/kv/skip (Cin = 2); all packed bf16 ----------------
__global__ __launch_bounds__(256) void k_qkvs_first(
    const float* __restrict__ nt, const float* __restrict__ rq,
    const float* __restrict__ qw, const float* __restrict__ qbv,
    const float* __restrict__ kw, const float* __restrict__ kbv,
    const float* __restrict__ vw, const float* __restrict__ vbv,
    const float* __restrict__ sw, const float* __restrict__ sbv,
    unsigned* __restrict__ q, unsigned short* __restrict__ kv, unsigned* __restrict__ sk)
{
  int idx = blockIdx.x * 256 + threadIdx.x;   // over NN*64
  if (idx >= NN * 64) return;
  int n = idx >> 6, l = idx & 63;
  int j0 = 2 * l, j1 = 2 * l + 1;
  float a = nt[n], b = rq[n];
  float q0 = (a * qw[2 * j0] + b * qw[2 * j0 + 1]) + qbv[j0];
  float q1 = (a * qw[2 * j1] + b * qw[2 * j1 + 1]) + qbv[j1];
  q[idx] = pk2(q0, q1);
  ushort4 kvo;
  kvo.x = f2bf((a * kw[2 * j0] + b * kw[2 * j0 + 1]) + kbv[j0]);
  kvo.y = f2bf((a * kw[2 * j1] + b * kw[2 * j1 + 1]) + kbv[j1]);
  kvo.z = f2bf((a * vw[2 * j0] + b * vw[2 * j0 + 1]) + vbv[j0]);
  kvo.w = f2bf((a * vw[2 * j1] + b * vw[2 * j1 + 1]) + vbv[j1]);
  ((ushort4*)kv)[idx] = kvo;
  float s0 = (a * sw[2 * j0] + b * sw[2 * j0 + 1]) + sbv[j0];
  float s1 = (a * sw[2 * j1] + b * sw[2 * j1 + 1]) + sbv[j1];
  sk[idx] = pk2(s0, s1);
}

// ---------------- qkvs layers 2..4 (Cin = 32): register tiles; q/skip packed bf16, kv packed bf16 ----------------
#define QP 36   // x pitch (floats)
#define WP 33   // W pitch (floats)
__global__ __launch_bounds__(256) void k_qkvs3(
    const float* __restrict__ yb, const float* __restrict__ stats,
    const float* __restrict__ bng, const float* __restrict__ bnb,
    const float* __restrict__ wq, const float* __restrict__ bq,
    const float* __restrict__ wk, const float* __restrict__ bk,
    const float* __restrict__ wv, const float* __restrict__ bv,
    const float* __restrict__ wsk, const float* __restrict__ bsk,
    unsigned* __restrict__ oq, unsigned short* __restrict__ okv, unsigned* __restrict__ osk)
{
  __shared__ __align__(16) float xs[64 * QP];
  __shared__ __align__(16) float Wl[2 * 128 * WP];

  const int t = threadIdx.x;
  const int nq = t & 15;
  const int chq = t >> 4;          // 0..15
  const int y = blockIdx.y;

  if (y == 1) {
    for (int idx = t; idx < 128 * 32; idx += 256) {
      int c = idx >> 5, k = idx & 31;
      Wl[c * WP + k] = wk[idx];
      Wl[128 * WP + c * WP + k] = wv[idx];
    }
  } else {
    const float* W = (y == 0) ? wq : wsk;
    for (int idx = t; idx < 128 * 32; idx += 256) {
      int c = idx >> 5, k = idx & 31;
      Wl[c * WP + k] = W[idx];
    }
  }

  const int ch0 = (t & 7) * 4;
  float sc[4], sh[4];
  #pragma unroll
  for (int c = 0; c < 4; ++c) {
    int ch = ch0 + c;
    float rsig = 1.0f / stats[32 + ch];
    sc[c] = bng[ch] * rsig;
    sh[c] = bnb[ch] - stats[ch] * sc[c];
  }

  const int ntiles = (NN + 63) / 64;
  for (int tile = blockIdx.x; tile < ntiles; tile += gridDim.x) {
    const int base = tile * 64;
    __syncthreads();
    #pragma unroll
    for (int rep = 0; rep < 2; ++rep) {
      int f = t + rep * 256;
      int n = f >> 3, kq = f & 7;
      int gn = base + n;
      if (gn >= NN) gn = NN - 1;
      float4 v = *(const float4*)(yb + (size_t)gn * 32 + kq * 4);
      v.x = fmaf(v.x, sc[0], sh[0]);
      v.y = fmaf(v.y, sc[1], sh[1]);
      v.z = fmaf(v.z, sc[2], sh[2]);
      v.w = fmaf(v.w, sc[3], sh[3]);
      *(float4*)(xs + n * QP + kq * 4) = v;
    }
    __syncthreads();

    if (y == 1) {
      float ak[4][8], av[4][8];
      #pragma unroll
      for (int s = 0; s < 4; ++s)
        #pragma unroll
        for (int j = 0; j < 8; ++j) { ak[s][j] = bk[chq * 8 + j]; av[s][j] = bv[chq * 8 + j]; }
      #pragma unroll 4
      for (int k2 = 0; k2 < 16; ++k2) {
        const int k = 2 * k2;
        float2 xv[4];
        #pragma unroll
        for (int s = 0; s < 4; ++s) xv[s] = *(const float2*)(xs + (nq + 16 * s) * QP + k);
        #pragma unroll
        for (int j = 0; j < 8; ++j) {
          float2 wk2 = *(const float2*)(Wl + (chq * 8 + j) * WP + k);
          float2 wv2 = *(const float2*)(Wl + 128 * WP + (chq * 8 + j) * WP + k);
          #pragma unroll
          for (int s = 0; s < 4; ++s) {
            ak[s][j] = fmaf(xv[s].x, wk2.x, ak[s][j]);
            ak[s][j] = fmaf(xv[s].y, wk2.y, ak[s][j]);
            av[s][j] = fmaf(xv[s].x, wv2.x, av[s][j]);
            av[s][j] = fmaf(xv[s].y, wv2.y, av[s][j]);
          }
        }
      }
      #pragma unroll
      for (int s = 0; s < 4; ++s) {
        int node = base + nq + 16 * s;
        if (node < NN) {
          uint4 A, B;
          A.x = pk2(ak[s][0], ak[s][1]); A.y = pk2(av[s][0], av[s][1]);
          A.z = pk2(ak[s][2], ak[s][3]); A.w = pk2(av[s][2], av[s][3]);
          B.x = pk2(ak[s][4], ak[s][5]); B.y = pk2(av[s][4], av[s][5]);
          B.z = pk2(ak[s][6], ak[s][7]); B.w = pk2(av[s][6], av[s][7]);
          unsigned short* dst = okv + (size_t)node * 256 + chq * 16;
          *(uint4*)dst = A;
          *(uint4*)(dst + 8) = B;
        }
      }
    } else {
      // y==0: q, y==2: skip — both packed bf16 (64 uints/node)
      const float* B = (y == 0) ? bq : bsk;
      unsigned* Of = (y == 0) ? oq : osk;
      float acc[4][8];
      #pragma unroll
      for (int s = 0; s < 4; ++s)
        #pragma unroll
        for (int j = 0; j < 8; ++j) acc[s][j] = B[chq * 8 + j];
      #pragma unroll 4
      for (int k2 = 0; k2 < 16; ++k2) {
        const int k = 2 * k2;
        float2 xv[4];
        #pragma unroll
        for (int s = 0; s < 4; ++s) xv[s] = *(const float2*)(xs + (nq + 16 * s) * QP + k);
        #pragma unroll
        for (int j = 0; j < 8; ++j) {
          float2 w2 = *(const float2*)(Wl + (chq * 8 + j) * WP + k);
          #pragma unroll
          for (int s = 0; s < 4; ++s) {
            acc[s][j] = fmaf(xv[s].x, w2.x, acc[s][j]);
            acc[s][j] = fmaf(xv[s].y, w2.y, acc[s][j]);
          }
        }
      }
      #pragma unroll
      for (int s = 0; s < 4; ++s) {
        int node = base + nq + 16 * s;
        if (node < NN) {
          uint4 Q;
          Q.x = pk2(acc[s][0], acc[s][1]);
          Q.y = pk2(acc[s][2], acc[s][3]);
          Q.z = pk2(acc[s][4], acc[s][5]);
          Q.w = pk2(acc[s][6], acc[s][7]);
          *(uint4*)(Of + (size_t)node * 64 + chq * 4) = Q;
        }
      }
    }
  }
}

// lin1: relu(BN(yb) @ W^T + b) -> 128 packed bf16
__global__ __launch_bounds__(256) void k_lin1d(
    const float* __restrict__ yb, const float* __restrict__ stats,
    const float* __restrict__ bng, const float* __restrict__ bnb,
    const float* __restrict__ W, const float* __restrict__ B, unsigned* __restrict__ O)
{
  __shared__ __align__(16) float xs[64 * QP];
  __shared__ __align__(16) float Wl[128 * WP];
  const int t = threadIdx.x;
  const int nq = t & 15;
  const int chq = t >> 4;
  for (int idx = t; idx < 128 * 32; idx += 256) {
    int c = idx >> 5, k = idx & 31;
    Wl[c * WP + k] = W[idx];
  }
  const int ch0 = (t & 7) * 4;
  float sc[4], sh[4];
  #pragma unroll
  for (int c = 0; c < 4; ++c) {
    int ch = ch0 + c;
    float rsig = 1.0f / stats[32 + ch];
    sc[c] = bng[ch] * rsig;
    sh[c] = bnb[ch] - stats[ch] * sc[c];
  }
  const int ntiles = (NN + 63) / 64;
  for (int tile = blockIdx.x; tile < ntiles; tile += gridDim.x) {
    const int base = tile * 64;
    __syncthreads();
    #pragma unroll
    for (int rep = 0; rep < 2; ++rep) {
      int f = t + rep * 256;
      int n = f >> 3, kq = f & 7;
      int gn = base + n;
      if (gn >= NN) gn = NN - 1;
      float4 v = *(const float4*)(yb + (size_t)gn * 32 + kq * 4);
      v.x = fmaf(v.x, sc[0], sh[0]);
      v.y = fmaf(v.y, sc[1], sh[1]);
      v.z = fmaf(v.z, sc[2], sh[2]);
      v.w = fmaf(v.w, sc[3], sh[3]);
      *(float4*)(xs + n * QP + kq * 4) = v;
    }
    __syncthreads();
    float acc[4][8];
    #pragma unroll
    for (int s = 0; s < 4; ++s)
      #pragma unroll
      for (int j = 0; j < 8; ++j) acc[s][j] = B[chq * 8 + j];
    #pragma unroll 4
    for (int k2 = 0; k2 < 16; ++k2) {
      const int k = 2 * k2;
      float2 xv[4];
      #pragma unroll
      for (int s = 0; s < 4; ++s) xv[s] = *(const float2*)(xs + (nq + 16 * s) * QP + k);
      #pragma unroll
      for (int j = 0; j < 8; ++j) {
        float2 w2 = *(const float2*)(Wl + (chq * 8 + j) * WP + k);
        #pragma unroll
        for (int s = 0; s < 4; ++s) {
          acc[s][j] = fmaf(xv[s].x, w2.x, acc[s][j]);
          acc[s][j] = fmaf(xv[s].y, w2.y, acc[s][j]);
        }
      }
    }
    #pragma unroll
    for (int s = 0; s < 4; ++s) {
      int node = base + nq + 16 * s;
      if (node < NN) {
        uint4 P;
        P.x = pk2(fmaxf(acc[s][0], 0.f), fmaxf(acc[s][1], 0.f));
        P.y = pk2(fmaxf(acc[s][2], 0.f), fmaxf(acc[s][3], 0.f));
        P.z = pk2(fmaxf(acc[s][4], 0.f), fmaxf(acc[s][5], 0.f));
        P.w = pk2(fmaxf(acc[s][6], 0.f), fmaxf(acc[s][7], 0.f));
        *(uint4*)(O + (size_t)node * 64 + chq * 4) = P;
      }
    }
  }
}

// ---------------- k_dense: packed-bf16 [NN x 128] @ W^T[128 x COUT] + relu ----------------
#define XPITCH 132
#define WPITCH 130
template<int COUT, bool STATS, bool REM>
__global__ __launch_bounds__(256) void k_dense(
    const unsigned* __restrict__ xin, const float* __restrict__ W,
    const float* __restrict__ bias, float* __restrict__ out,
    double* __restrict__ psum, double* __restrict__ psq,
    const float* __restrict__ rw, const float* __restrict__ rb,
    const float* __restrict__ amask, float* __restrict__ rl)
{
  constexpr int JB = COUT / 16;   // channels per thread
  __shared__ __align__(16) float xs[64 * XPITCH];
  __shared__ float Ws[COUT * WPITCH];
  __shared__ float rem_lds[REM ? 16 * 64 : 1];

  const int t = threadIdx.x;
  const int nq = t & 15;
  const int chq = t >> 4;

  for (int idx = t; idx < COUT * 128; idx += 256) {
    int c = idx >> 7, k = idx & 127;
    Ws[c * WPITCH + k] = W[idx];
  }
  float bj[JB];
  float rwj[REM ? JB : 1];
  #pragma unroll
  for (int j = 0; j < JB; ++j) {
    bj[j] = bias[chq * JB + j];
    if (REM) rwj[j] = rw[chq * JB + j];
  }
  double sd[STATS ? JB : 1], sq[STATS ? JB : 1];
  if (STATS) {
    #pragma unroll
    for (int j = 0; j < JB; ++j) { sd[j] = 0.0; sq[j] = 0.0; }
  }

  const uint4* xin4 = (const uint4*)xin;
  const int ntiles = (NN + 63) / 64;
  for (int tile = blockIdx.x; tile < ntiles; tile += gridDim.x) {
    const int base = tile * 64;
    __syncthreads();
    // stage: 64 nodes x 16 uint4 (128 bf16 each) -> f32 LDS tile
    #pragma unroll
    for (int r = 0; r < 4; ++r) {
      int f = t + r * 256;              // 1024 uint4 slots
      int n = f >> 4, kq = f & 15;
      int gn = base + n;
      if (gn >= NN) gn = NN - 1;
      uint4 v = xin4[(size_t)gn * 16 + kq];
      float* d = xs + n * XPITCH + kq * 8;
      float4 lo, hi;
      lo.x = bf2f(LO16(v.x)); lo.y = bf2f(HI16(v.x));
      lo.z = bf2f(LO16(v.y)); lo.w = bf2f(HI16(v.y));
      hi.x = bf2f(LO16(v.z)); hi.y = bf2f(HI16(v.z));
      hi.z = bf2f(LO16(v.w)); hi.w = bf2f(HI16(v.w));
      *(float4*)d = lo;
      *(float4*)(d + 4) = hi;
    }
    __syncthreads();

    float acc[4][JB];
    #pragma unroll
    for (int s = 0; s < 4; ++s)
      #pragma unroll
      for (int j = 0; j < JB; ++j) acc[s][j] = bj[j];

    #pragma unroll 8
    for (int k2 = 0; k2 < 64; ++k2) {
      const int k = 2 * k2;
      float2 xv[4];
      #pragma unroll
      for (int s = 0; s < 4; ++s)
        xv[s] = *(const float2*)(xs + (nq + 16 * s) * XPITCH + k);
      float2 wv[JB];
      #pragma unroll
      for (int j = 0; j < JB; ++j)
        wv[j] = *(const float2*)(Ws + (chq * JB + j) * WPITCH + k);
      #pragma unroll
      for (int s = 0; s < 4; ++s)
        #pragma unroll
        for (int j = 0; j < JB; ++j) {
          acc[s][j] = fmaf(xv[s].x, wv[j].x, acc[s][j]);
          acc[s][j] = fmaf(xv[s].y, wv[j].y, acc[s][j]);
        }
    }

    #pragma unroll
    for (int s = 0; s < 4; ++s) {
      const int node = base + nq + 16 * s;
      const bool ok = node < NN;
      #pragma unroll
      for (int j = 0; j < JB; ++j) acc[s][j] = fmaxf(acc[s][j], 0.f);
      if (ok) {
        if (COUT == 32) {
          *(float2*)(out + (size_t)node * 32 + chq * 2) = make_float2(acc[s][0], acc[s][1]);
        } else {
          *(float4*)(out + (size_t)node * 64 + chq * 4) =
              make_float4(acc[s][0], acc[s][1], acc[s][2], acc[s][3]);
        }
      }
      if (STATS && ok) {
        #pragma unroll
        for (int j = 0; j < JB; ++j) {
          sd[j] += (double)acc[s][j];
          sq[j] += (double)acc[s][j] * (double)acc[s][j];
        }
      }
      if (REM) {
        float p = 0.f;
        #pragma unroll
        for (int j = 0; j < JB; ++j) p = fmaf(acc[s][j], rwj[j], p);
        rem_lds[chq * 64 + nq + 16 * s] = p;
      }
    }

    if (REM) {
      __syncthreads();
      if (t < 64) {
        int node = base + t;
        if (node < NN) {
          float v = rb[0];
          #pragma unroll
          for (int c = 0; c < 16; ++c) v += rem_lds[c * 64 + t];
          float mv = amask[node];
          float mterm;
          if (node < 15) mterm = (mv == 0.f) ? -INFINITY : ((mv == -INFINITY) ? 0.f : mv);
          else mterm = mv;
          rl[node] = fmaxf(v + mterm, NEGBIG);
        }
      }
    }
  }

  if (STATS) {
    __shared__ double sred[256 * 2];
    __syncthreads();
    #pragma unroll
    for (int j = 0; j < JB; ++j) { sred[t * 2 + j] = sd[j]; }
    __syncthreads();
    if (t < 32) {
      int cq = t >> 1, j = t & 1;
      double a = 0.0;
      #pragma unroll
      for (int n = 0; n < 16; ++n) a += sred[(cq * 16 + n) * 2 + j];
      psum[blockIdx.x * 32 + t] = a;
    }
    __syncthreads();
    #pragma unroll
    for (int j = 0; j < JB; ++j) { sred[t * 2 + j] = sq[j]; }
    __syncthreads();
    if (t < 32) {
      int cq = t >> 1, j = t & 1;
      double a = 0.0;
      #pragma unroll
      for (int n = 0; n < 16; ++n) a += sred[(cq * 16 + n) * 2 + j];
      psq[blockIdx.x * 32 + t] = a;
    }
  }
}

// parallel BN-stats finalize over NDB partials
__global__ __launch_bounds__(1024) void k_stats2(
    const double* __restrict__ psum, const double* __restrict__ psq, float* __restrict__ stats)
{
  const int t = threadIdx.x;
  const int ch = t & 31;
  const int chunk = t >> 5;
  double s = 0.0, q = 0.0;
  for (int b = chunk; b < NDB; b += 32) { s += psum[b * 32 + ch]; q += psq[b * 32 + ch]; }
  __shared__ double rs[1024];
  __shared__ double rq[1024];
  rs[t] = s; rq[t] = q;
  __syncthreads();
  for (int off = 16; off > 0; off >>= 1) {
    if (chunk < off) { rs[t] += rs[t + off * 32]; rq[t] += rq[t + off * 32]; }
    __syncthreads();
  }
  if (t < 32) {
    double mu = rs[t] / (double)NN;
    double var = rq[t] / (double)NN - mu * mu;
    if (var < 0.0) var = 0.0;
    stats[t] = (float)mu;
    stats[32 + t] = sqrtf((float)var + 1e-5f);
  }
}

// ---------------- attention: one wave per dst node, direct-exp softmax, 8-deep gather ----------------
// skip/h packed bf16 (64 uints per node)
__global__ __launch_bounds__(256) void k_attn(
    const unsigned* __restrict__ qb, const unsigned short* __restrict__ kvb,
    unsigned* __restrict__ skh,
    const int* __restrict__ rowptr, const int2* __restrict__ csr,
    const float* __restrict__ ew, const float* __restrict__ bw)
{
  const int wid = (blockIdx.x * 256 + threadIdx.x) >> 6;
  const int lane = threadIdx.x & 63;
  if (wid >= NN) return;
  const unsigned qu = qb[(size_t)wid * 64 + lane];
  const float qx = bf2f(LO16(qu));
  const float qy = bf2f(HI16(qu));
  const float2 ew2 = ((const float2*)ew)[lane];
  const ushort4* kvp = (const ushort4*)kvb;
  const int p0 = rowptr[wid], p1 = rowptr[wid + 1];

  float s = 0.f, accx = 0.f, accy = 0.f;
  const float iscale = 0.17677669529663689f;  // 1/sqrt(32)

#define EDGE_BODY(cc, kv) {                                            \
    float lat = __int_as_float(cc.y);                                  \
    float e0 = lat * ew2.x, e1 = lat * ew2.y;                          \
    float kx = bf2f(kv.x) + e0, ky = bf2f(kv.y) + e1;                  \
    float part = qx * kx + qy * ky;                                    \
    part += __shfl_xor(part, 1);                                       \
    part += __shfl_xor(part, 2);                                       \
    part += __shfl_xor(part, 4);                                       \
    part += __shfl_xor(part, 8);                                       \
    float pt = __expf(part * iscale);                                  \
    float vx = bf2f(kv.z) + e0, vy = bf2f(kv.w) + e1;                  \
    s += pt;                                                           \
    accx = fmaf(pt, vx, accx);                                         \
    accy = fmaf(pt, vy, accy); }

  int p = p0;
  for (; p + 7 < p1; p += 8) {
    int2 c0 = csr[p],     c1 = csr[p + 1], c2 = csr[p + 2], c3 = csr[p + 3];
    int2 c4 = csr[p + 4], c5 = csr[p + 5], c6 = csr[p + 6], c7 = csr[p + 7];
    ushort4 kv0 = kvp[(size_t)c0.x * 64 + lane];
    ushort4 kv1 = kvp[(size_t)c1.x * 64 + lane];
    ushort4 kv2 = kvp[(size_t)c2.x * 64 + lane];
    ushort4 kv3 = kvp[(size_t)c3.x * 64 + lane];
    ushort4 kv4 = kvp[(size_t)c4.x * 64 + lane];
    ushort4 kv5 = kvp[(size_t)c5.x * 64 + lane];
    ushort4 kv6 = kvp[(size_t)c6.x * 64 + lane];
    ushort4 kv7 = kvp[(size_t)c7.x * 64 + lane];
    EDGE_BODY(c0, kv0)
    EDGE_BODY(c1, kv1)
    EDGE_BODY(c2, kv2)
    EDGE_BODY(c3, kv3)
    EDGE_BODY(c4, kv4)
    EDGE_BODY(c5, kv5)
    EDGE_BODY(c6, kv6)
    EDGE_BODY(c7, kv7)
  }
  for (; p + 3 < p1; p += 4) {
    int2 c0 = csr[p], c1 = csr[p + 1], c2 = csr[p + 2], c3 = csr[p + 3];
    ushort4 kv0 = kvp[(size_t)c0.x * 64 + lane];
    ushort4 kv1 = kvp[(size_t)c1.x * 64 + lane];
    ushort4 kv2 = kvp[(size_t)c2.x * 64 + lane];
    ushort4 kv3 = kvp[(size_t)c3.x * 64 + lane];
    EDGE_BODY(c0, kv0)
    EDGE_BODY(c1, kv1)
    EDGE_BODY(c2, kv2)
    EDGE_BODY(c3, kv3)
  }
  for (; p < p1; ++p) {
    int2 c0 = csr[p];
    ushort4 kv0 = kvp[(size_t)c0.x * 64 + lane];
    EDGE_BODY(c0, kv0)
  }
#undef EDGE_BODY

  float inv = (s > 0.f) ? (1.0f / s) : 1.0f;
  float ox = accx * inv, oy = accy * inv;

  unsigned su = skh[(size_t)wid * 64 + lane];
  float skx = bf2f(LO16(su));
  float sky = bf2f(HI16(su));
  const float2* bw2 = (const float2*)bw;
  float2 b1 = bw2[lane], b2 = bw2[64 + lane], b3 = bw2[128 + lane];
  float part = b1.x * ox + b1.y * oy + b2.x * skx + b2.y * sky
             + b3.x * (ox - skx) + b3.y * (oy - sky);
  #pragma unroll
  for (int off = 1; off < 64; off <<= 1) part += __shfl_xor(part, off);
  float beta = 1.f / (1.f + __expf(-part));
  float hx = beta * skx + (1.f - beta) * ox;
  float hy = beta * sky + (1.f - beta) * oy;
  skh[(size_t)wid * 64 + lane] = pk2(hx, hy);
}

// ---------------- sampling machinery ----------------
__global__ __launch_bounds__(256) void k_pass(
    const float* __restrict__ lg,
    float* __restrict__ pm, float* __restrict__ ps, float* __restrict__ pg, int* __restrict__ pidx,
    unsigned ka, unsigned kb)
{
  float m = -INFINITY, s = 0.f, g = -INFINITY; int gi = INT_MAX; bool hg = false;
  for (int i = blockIdx.x * 256 + threadIdx.x; i < NN; i += gridDim.x * 256) {
    float v = lg[i];
    if (v > m) { s = (m == -INFINITY) ? 1.f : fmaf(s, expf(m - v), 1.f); m = v; }
    else if (v != -INFINITY) s += expf(v - m);
    float tot = v + gumbel_of(ka, kb, i);
    if (!hg || tot > g || (tot == g && i < gi)) { g = tot; gi = i; hg = true; }
  }
  __shared__ float sm[256], ss[256], sg[256]; __shared__ int si[256];
  int t = threadIdx.x;
  sm[t] = m; ss[t] = s; sg[t] = g; si[t] = gi;
  __syncthreads();
  for (int off = 128; off > 0; off >>= 1) {
    if (t < off) {
      float m2 = sm[t + off], s2 = ss[t + off];
      float M = fmaxf(sm[t], m2);
      float sn = 0.f;
      if (M != -INFINITY) {
        if (sm[t] != -INFINITY) sn += ss[t] * expf(sm[t] - M);
        if (m2 != -INFINITY) sn += s2 * expf(m2 - M);
      }
      sm[t] = M; ss[t] = sn;
      float g2 = sg[t + off]; int i2 = si[t + off];
      if (g2 > sg[t] || (g2 == sg[t] && i2 < si[t])) { sg[t] = g2; si[t] = i2; }
    }
    __syncthreads();
  }
  if (t == 0) { pm[blockIdx.x] = sm[0]; ps[blockIdx.x] = ss[0]; pg[blockIdx.x] = sg[0]; pidx[blockIdx.x] = si[0]; }
}

// choose + optional fused proj (aw != nullptr only for the first draw)
__global__ __launch_bounds__(PB) void k_choose(
    const float* __restrict__ lg,
    const float* __restrict__ pm, const float* __restrict__ ps,
    const float* __restrict__ pg, const int* __restrict__ pidx,
    float* __restrict__ act_out, float* __restrict__ lp_out, int* __restrict__ a_scr,
    const float* __restrict__ xf, const float* __restrict__ aw,
    const float* __restrict__ ab, float* __restrict__ proj)
{
  __shared__ float sm[PB], ss[PB], sg[PB]; __shared__ int si[PB];
  __shared__ float xs2[64];
  int t = threadIdx.x;
  sm[t] = pm[t]; ss[t] = ps[t]; sg[t] = pg[t]; si[t] = pidx[t];
  __syncthreads();
  for (int off = PB / 2; off > 0; off >>= 1) {
    if (t < off) {
      float m2 = sm[t + off], s2 = ss[t + off];
      float M = fmaxf(sm[t], m2);
      float sn = 0.f;
      if (M != -INFINITY) {
        if (sm[t] != -INFINITY) sn += ss[t] * expf(sm[t] - M);
        if (m2 != -INFINITY) sn += s2 * expf(m2 - M);
      }
      sm[t] = M; ss[t] = sn;
      float g2 = sg[t + off]; int i2 = si[t + off];
      if (g2 > sg[t] || (g2 == sg[t] && i2 < si[t])) { sg[t] = g2; si[t] = i2; }
    }
    __syncthreads();
  }
  if (t == 0) {
    int a = si[0];
    a_scr[0] = a;
    act_out[0] = (float)a;
    lp_out[0] = (lg[a] - sm[0]) - logf(ss[0]);
  }
  if (aw != nullptr) {
    __syncthreads();
    int a = si[0];
    if (t < 64) xs2[t] = xf[(size_t)a * 64 + t];
    __syncthreads();
    if (t < 64) {
      float acc = 0.f;
      #pragma unroll
      for (int i = 0; i < 64; ++i) acc = fmaf(xs2[i], aw[t * 64 + i], acc);
      proj[t] = tanhf(acc + ab[t]);
    }
  }
}

__global__ __launch_bounds__(256) void k_nl(
    const float* __restrict__ xf, const float* __restrict__ proj,
    const float* __restrict__ amask, const int* __restrict__ a1p, float* __restrict__ nl)
{
  int wid = (blockIdx.x * 256 + threadIdx.x) >> 6;
  int lane = threadIdx.x & 63;
  if (wid >= NN) return;
  float part = xf[(size_t)wid * 64 + lane] * proj[lane];
  #pragma unroll
  for (int off = 1; off < 64; off <<= 1) part += __shfl_xor(part, off);
  if (lane == 0) {
    int a1 = a1p[0];
    float mv = (wid == a1) ? 0.f : amask[wid];
    nl[wid] = fmaxf(part + mv, NEGBIG);
  }
}

// ---------------- host ----------------
extern "C" void kernel_launch(void* const* d_in, const int* in_sizes, int n_in,
                              void* d_out, int out_size, void* d_ws, size_t ws_size,
                              hipStream_t stream)
{
  (void)in_sizes; (void)n_in; (void)out_size; (void)ws_size;

  const float* node_type = (const float*)d_in[0];
  const float* requests  = (const float*)d_in[1];
  const float* latency   = (const float*)d_in[2];
  const float* amask     = (const float*)d_in[3];
  const int*   eidx      = (const int*)d_in[4];
  const int* esrc = eidx;
  const int* edst = eidx + NE;

  const float* q1_w = (const float*)d_in[5];  const float* q1_b = (const float*)d_in[6];
  const float* k1_w = (const float*)d_in[7];  const float* k1_b = (const float*)d_in[8];
  const float* v1_w = (const float*)d_in[9];  const float* v1_b = (const float*)d_in[10];
  const float* e1_w = (const float*)d_in[11];
  const float* sk1_w = (const float*)d_in[12]; const float* sk1_b = (const float*)d_in[13];
  const float* be1_w = (const float*)d_in[14];
  const float* tf1_w = (const float*)d_in[15]; const float* tf1_b = (const float*)d_in[16];
  const float* bn1_g = (const float*)d_in[17]; const float* bn1_b = (const float*)d_in[18];
  const float* qL_w = (const float*)d_in[19]; const float* qL_b = (const float*)d_in[20];
  const float* kL_w = (const float*)d_in[21]; const float* kL_b = (const float*)d_in[22];
  const float* vL_w = (const float*)d_in[23]; const float* vL_b = (const float*)d_in[24];
  const float* eL_w = (const float*)d_in[25];
  const float* skL_w = (const float*)d_in[26]; const float* skL_b = (const float*)d_in[27];
  const float* beL_w = (const float*)d_in[28];
  const float* tfL_w = (const float*)d_in[29]; const float* tfL_b = (const float*)d_in[30];
  const float* bnL_g = (const float*)d_in[31]; const float* bnL_b = (const float*)d_in[32];
  const float* l1_w = (const float*)d_in[33]; const float* l1_b = (const float*)d_in[34];
  const float* l2_w = (const float*)d_in[35]; const float* l2_b = (const float*)d_in[36];
  const float* rem_w = (const float*)d_in[37]; const float* rem_b = (const float*)d_in[38];
  const float* ap_w = (const float*)d_in[39]; const float* ap_b = (const float*)d_in[40];

  // workspace layout (~130 MB)
  char* ws = (char*)d_ws;
  size_t off = 0;
  auto alloc = [&](size_t bytes) -> void* {
    void* p = ws + off;
    off += (bytes + 255) & ~(size_t)255;
    return p;
  };
  unsigned* qbuf = (unsigned*)alloc((size_t)NN * 64 * 4);                // packed q bf16
  unsigned short* kvbuf = (unsigned short*)alloc((size_t)NN * 256 * 2);  // packed k,v bf16
  unsigned* skb = (unsigned*)alloc((size_t)NN * 64 * 4);  // packed skip in / h out (bf16)
  float* yb   = (float*)alloc((size_t)NN * 32 * 4);       // relu(transf) pre-BN (f32)
  int*   rowptr = (int*)alloc((size_t)(NN + 1) * 4);
  int*   deg    = (int*)alloc((size_t)NN * 4);
  int*   fill   = (int*)alloc((size_t)NN * 4);
  int2*  csr    = (int2*)alloc((size_t)NE * 8);           // packed (src, lat)
  double* psum = (double*)alloc((size_t)NDB * 32 * 8);
  double* psq  = (double*)alloc((size_t)NDB * 32 * 8);
  float* stats = (float*)alloc(64 * 4);
  float* pm = (float*)alloc(PB * 4);
  float* ps = (float*)alloc(PB * 4);
  float* pg = (float*)alloc(PB * 4);
  int*   pidx = (int*)alloc(PB * 4);
  float* proj = (float*)alloc(64 * 4);
  int*   a_scr = (int*)alloc(2 * 4);
  unsigned* y1 = skb;         // lin1 output (packed bf16) reuses skb
  float* xf = (float*)kvbuf;  // lin2 output (f32) reuses kv buffer

  // JAX PRNG: key(42) -> foldlike split -> (k1, k2)
  unsigned k1a, k1b, k2a, k2b;
  tf_host(0u, 42u, 0u, 0u, &k1a, &k1b);
  tf_host(0u, 42u, 0u, 1u, &k2a, &k2b);

  float* dout = (float*)d_out;

  // CSR build (reused by all 4 conv layers)
  k_zero2<<<(NN + 255) / 256, 256, 0, stream>>>(deg, fill);
  k_hist<<<(NE + 255) / 256, 256, 0, stream>>>(edst, deg);
  k_scan<<<1, 1024, 0, stream>>>(deg, rowptr);
  k_scatter<<<(NE + 255) / 256, 256, 0, stream>>>(esrc, edst, latency, rowptr, fill, csr);

  // ---- conv layer 1 (Cin=2) ----
  k_qkvs_first<<<(NN * 64 + 255) / 256, 256, 0, stream>>>(
      node_type, requests, q1_w, q1_b, k1_w, k1_b, v1_w, v1_b, sk1_w, sk1_b,
      qbuf, kvbuf, skb);
  k_attn<<<NN / 4, 256, 0, stream>>>(qbuf, kvbuf, skb, rowptr, csr, e1_w, be1_w);
  k_dense<32, true, false><<<NDB, 256, 0, stream>>>(skb, tf1_w, tf1_b, yb, psum, psq,
                                                    nullptr, nullptr, nullptr, nullptr);
  k_stats2<<<1, 1024, 0, stream>>>(psum, psq, stats);

  // ---- conv layers 2..4 (Cin=32), BN of previous layer fused into qkvs load ----
  for (int i = 0; i < 3; ++i) {
    const float* g = (i == 0) ? bn1_g : bnL_g + (i - 1) * 32;
    const float* b = (i == 0) ? bn1_b : bnL_b + (i - 1) * 32;
    k_qkvs3<<<dim3(NDB, 3), 256, 0, stream>>>(
        yb, stats, g, b,
        qL_w + i * 4096, qL_b + i * 128,
        kL_w + i * 4096, kL_b + i * 128,
        vL_w + i * 4096, vL_b + i * 128,
        skL_w + i * 4096, skL_b + i * 128,
        qbuf, kvbuf, skb);
    k_attn<<<NN / 4, 256, 0, stream>>>(qbuf, kvbuf, skb, rowptr, csr,
                                       eL_w + i * 128, beL_w + i * 384);
    k_dense<32, true, false><<<NDB, 256, 0, stream>>>(skb, tfL_w + i * 4096, tfL_b + i * 32,
                                                      yb, psum, psq,
                                                      nullptr, nullptr, nullptr, nullptr);
    k_stats2<<<1, 1024, 0, stream>>>(psum, psq, stats);
  }

  // ---- MLP (BN of layer-4 fused into lin1 load); rem head fused into lin2 ----
  k_lin1d<<<NDB, 256, 0, stream>>>(yb, stats, bnL_g + 2 * 32, bnL_b + 2 * 32, l1_w, l1_b, y1);
  k_dense<64, false, true><<<NDB, 256, 0, stream>>>(y1, l2_w, l2_b, xf, nullptr, nullptr,
                                                    rem_w, rem_b, amask, dout);

  // ---- sampling ----
  k_pass<<<PB, 256, 0, stream>>>(dout, pm, ps, pg, pidx, k1a, k1b);
  k_choose<<<1, PB, 0, stream>>>(dout, pm, ps, pg, pidx,
                                 dout + 2 * NN, dout + 2 * NN + 2, a_scr,
                                 xf, ap_w, ap_b, proj);
  k_nl<<<NN / 4, 256, 0, stream>>>(xf, proj, amask, a_scr, dout + NN);
  k_pass<<<PB, 256, 0, stream>>>(dout + NN, pm, ps, pg, pidx, k2a, k2b);
  k_choose<<<1, PB, 0, stream>>>(dout + NN, pm, ps, pg, pidx,
                                 dout + 2 * NN + 1, dout + 2 * NN + 3, a_scr + 1,
                                 nullptr, nullptr, nullptr, nullptr);
}